// Round 2
// baseline (47.502 us; speedup 1.0000x reference)
//
#include <hip/hip_runtime.h>

// y[b,n] = x[b,n] * (window[n%512] + window[n%512 + 512])
//
// Derivation: reference is WOLA segment->unsegment with sqrt'd windows.
// y = x * sum_k wmat[k, n-k*hop]^2. wmat^2 undoes the sqrt; the edge-corrected
// pre/post windows exactly compensate the missing neighbor frame at both ends,
// so the summed gain is uniformly periodic with period hop=512:
//   g[r] = window[r] + window[r+512],  r = n mod 512.
// => pure elementwise multiply: 268 MB compulsory traffic, ~43us HBM roofline.
//
// R1: 45.8us (93% of copy ceiling), VGPR=8 -> only 1 float4 in flight/thread.
// R2: unroll x4 for MLP=4, non-temporal stores so y doesn't evict x from L3
//     (FETCH was already ~half L3-hit).

typedef float float4v __attribute__((ext_vector_type(4)));

__global__ __launch_bounds__(256) void Segmenter_23596550324744_kernel(
    const float* __restrict__ x,
    const float* __restrict__ window,
    float* __restrict__ y,
    long long n4_total) {
    const long long tid = (long long)blockIdx.x * blockDim.x + threadIdx.x;
    const long long stride = (long long)gridDim.x * blockDim.x;  // multiple of 128 by launch config

    // Position within the 512-float period, in float4 units. The grid-stride
    // (in float4s) is a multiple of 128, so this is loop-invariant: load the
    // 4 gain values once into registers.
    const int r = (int)(tid & 127) * 4;
    float4v g;
    g.x = window[r + 0] + window[r + 512];
    g.y = window[r + 1] + window[r + 513];
    g.z = window[r + 2] + window[r + 514];
    g.w = window[r + 3] + window[r + 515];

    const float4v* __restrict__ x4 = (const float4v*)x;
    float4v* __restrict__ y4 = (float4v*)y;

    long long i = tid;
    // Main unrolled loop: 4 independent loads in flight, then 4 nt-stores.
    for (; i + 3 * stride < n4_total; i += 4 * stride) {
        float4v a0 = x4[i];
        float4v a1 = x4[i + stride];
        float4v a2 = x4[i + 2 * stride];
        float4v a3 = x4[i + 3 * stride];
        __builtin_nontemporal_store(a0 * g, &y4[i]);
        __builtin_nontemporal_store(a1 * g, &y4[i + stride]);
        __builtin_nontemporal_store(a2 * g, &y4[i + 2 * stride]);
        __builtin_nontemporal_store(a3 * g, &y4[i + 3 * stride]);
    }
    // Tail (not taken for the bench shape: 2^23 = 16 * 2^19 exactly).
    for (; i < n4_total; i += stride) {
        __builtin_nontemporal_store(x4[i] * g, &y4[i]);
    }
}

extern "C" void kernel_launch(void* const* d_in, const int* in_sizes, int n_in,
                              void* d_out, int out_size, void* d_ws, size_t ws_size,
                              hipStream_t stream) {
    const float* x = (const float*)d_in[0];
    const float* window = (const float*)d_in[1];
    float* y = (float*)d_out;

    const long long n_total = (long long)in_sizes[0];  // 16 * 2097152 = 2^25
    const long long n4_total = n_total / 4;            // 2^23

    // 2048 blocks x 256 threads = 2^19 threads: stride in float4 units is a
    // multiple of 128 (the 512-float period / 4), keeping each thread's
    // gain registers loop-invariant. 16 float4s per thread = 4 unrolled iters.
    const int block = 256;
    const int grid = 2048;
    Segmenter_23596550324744_kernel<<<grid, block, 0, stream>>>(x, window, y, n4_total);
}

// Round 3
// 44.263 us; speedup vs baseline: 1.0732x; 1.0732x over previous
//
#include <hip/hip_runtime.h>

// y[b,n] = x[b,n] * (window[n%512] + window[n%512 + 512])
//
// Derivation: reference is WOLA segment->unsegment with sqrt'd windows.
// y = x * sum_k wmat[k, n-k*hop]^2. wmat^2 undoes the sqrt; the edge-corrected
// pre/post windows exactly compensate the missing neighbor frame at both ends,
// so the summed gain is uniformly periodic with period hop=512:
//   g[r] = window[r] + window[r+512],  r = n mod 512.
// => pure elementwise multiply: 268 MB compulsory traffic, 42.6us floor at the
//    6.29 TB/s measured copy ceiling.
//
// R1: simple loop, 45.8us (93% of ceiling). VGPR=8.
// R2: unroll x4 + nt stores REGRESSED to 47.5us; FETCH unchanged => nt has no
//     L3/MALL effect; regression was the unroll's bursty store clustering.
// R3: revert unroll (simple dependent-chain loop won), keep nt store as a
//     neutral L2 hint, grid 2048->4096 for smoother ramp/drain.

typedef float float4v __attribute__((ext_vector_type(4)));

__global__ __launch_bounds__(256) void Segmenter_23596550324744_kernel(
    const float* __restrict__ x,
    const float* __restrict__ window,
    float* __restrict__ y,
    long long n4_total) {
    const long long tid = (long long)blockIdx.x * blockDim.x + threadIdx.x;
    const long long stride = (long long)gridDim.x * blockDim.x;  // multiple of 128 float4s

    // Position within the 512-float period, in float4 units. The grid-stride
    // (in float4s) is a multiple of 128, so this is loop-invariant: load the
    // 4 gain values once into registers.
    const int r = (int)(tid & 127) * 4;
    float4v g;
    g.x = window[r + 0] + window[r + 512];
    g.y = window[r + 1] + window[r + 513];
    g.z = window[r + 2] + window[r + 514];
    g.w = window[r + 3] + window[r + 515];

    const float4v* __restrict__ x4 = (const float4v*)x;
    float4v* __restrict__ y4 = (float4v*)y;
    for (long long i = tid; i < n4_total; i += stride) {
        __builtin_nontemporal_store(x4[i] * g, &y4[i]);
    }
}

extern "C" void kernel_launch(void* const* d_in, const int* in_sizes, int n_in,
                              void* d_out, int out_size, void* d_ws, size_t ws_size,
                              hipStream_t stream) {
    const float* x = (const float*)d_in[0];
    const float* window = (const float*)d_in[1];
    float* y = (float*)d_out;

    const long long n_total = (long long)in_sizes[0];  // 16 * 2097152 = 2^25
    const long long n4_total = n_total / 4;            // 2^23

    // block=256 keeps the float4 grid-stride a multiple of 128 (the 512-float
    // period), so each thread's gain registers are loop-invariant.
    // 4096 blocks = 2^20 threads -> 8 float4 iterations per thread.
    const int block = 256;
    const int grid = 4096;
    Segmenter_23596550324744_kernel<<<grid, block, 0, stream>>>(x, window, y, n4_total);
}